// Round 12
// baseline (513.438 us; speedup 1.0000x reference)
//
#include <hip/hip_runtime.h>

// MultiHeadRouter: B=2, L=4096, H=16, S=64, D=128
// out (float32): [T*H ones][T*H argmax-as-float][1 loss], T = 8192
//
// R12 = R10 pipeline (unchanged, best @34.9us) + 4 DIAGNOSTIC PROBES.
// Probes mirror R10's router phases at ITER-scale so each cracks the rocprof
// top-5 and yields per-phase dur + counters. They write only to ws scratch
// (disjoint from wfrag/ws_sums/ws_cnts), keepalive'd against DCE (rule 17).
// This round's dur_us is intentionally sacrificed for the decomposition.

#define TOKENS  8192
#define NHEAD   16
#define NSTATE  64
#define DDIM    128
#define TH      (TOKENS * NHEAD)
#define WFRAG_BYTES (1u << 19)   // 512 KB: 16 heads x 32 KB fragment planes

typedef _Float16 half8 __attribute__((ext_vector_type(8)));
typedef float    f32x4 __attribute__((ext_vector_type(4)));

constexpr int TPW   = 16;
constexpr int WAVES = 4;
constexpr int TPB   = TPW * WAVES;           // 64
constexpr int BPH   = TOKENS / TPB;          // 128
constexpr int NBLK  = NHEAD * BPH;           // 2048

#define GLOAD_LDS16(gsrc, ldst)                                           \
    __builtin_amdgcn_global_load_lds(                                     \
        (const __attribute__((address_space(1))) void*)(gsrc),            \
        (__attribute__((address_space(3))) void*)(ldst), 16, 0, 0)

#define KEEP(v)  asm volatile("" :: "v"(v))
#define OPAQ(v)  asm volatile("" : "+v"(v))

__device__ __forceinline__ unsigned int ordf(float f) {
    unsigned int u = __float_as_uint(f);
    return (u & 0x80000000u) ? ~u : (u | 0x80000000u);
}

__device__ __forceinline__ void split8(const f32x4 v0, const f32x4 v1,
                                       half8& hh, half8& ll) {
    #pragma unroll
    for (int j = 0; j < 4; ++j) {
        _Float16 h0 = (_Float16)v0[j];
        hh[j]     = h0;  ll[j]     = (_Float16)(v0[j] - (float)h0);
        _Float16 h1 = (_Float16)v1[j];
        hh[4 + j] = h1;  ll[4 + j] = (_Float16)(v1[j] - (float)h1);
    }
}

// ---------------- real pipeline (R10 verbatim) ----------------

__global__ __launch_bounds__(256)
void prep_w(const float* __restrict__ w, half8* __restrict__ wfrag)
{
    const int t    = blockIdx.x * 256 + threadIdx.x;
    const int lane = t & 63;
    const int n    = (t >> 6) & 3;
    const int ks   = (t >> 8) & 3;
    const int h    = t >> 10;
    const int s    = n * 16 + (lane & 15);
    const int k0   = ks * 32 + (lane >> 4) * 8;
    const float* src = w + (size_t)(h * NSTATE + s) * DDIM + k0;
    f32x4 v0 = *reinterpret_cast<const f32x4*>(src);
    f32x4 v1 = *reinterpret_cast<const f32x4*>(src + 4);
    half8 hv, lv;
    split8(v0, v1, hv, lv);
    const size_t hb = (size_t)h * 2048;
    const int fb = (ks * 4 + n) * 2;
    wfrag[hb + (size_t)fb * 64 + lane]       = hv;
    wfrag[hb + (size_t)(fb + 1) * 64 + lane] = lv;
}

__global__ __launch_bounds__(256)
void router_mfma(const float* __restrict__ x,
                 const half8* __restrict__ wfrag,
                 const float* __restrict__ bias,
                 float* __restrict__ out,
                 float* __restrict__ ws_sums,
                 int*   __restrict__ ws_cnts)
{
    __shared__ __align__(16) unsigned char smem[32768];

    const int blk  = blockIdx.x;
    const int h    = blk & 15;
    const int bi   = blk >> 4;
    const int tid  = threadIdx.x;
    const int wave = __builtin_amdgcn_readfirstlane(tid >> 6);
    const int lane = tid & 63;
    const int col  = lane & 15;
    const int kg   = lane >> 4;
    const int tokb = bi * TPB + wave * TPW;

    const size_t srow = (size_t)(NHEAD * DDIM);
    const float* arow = x + (size_t)(tokb + col) * srow + h * DDIM + kg * 8;

    f32x4 g[4][2];
    #pragma unroll
    for (int ks = 0; ks < 4; ++ks) {
        g[ks][0] = *reinterpret_cast<const f32x4*>(arow + ks * 32);
        g[ks][1] = *reinterpret_cast<const f32x4*>(arow + ks * 32 + 4);
    }

    {
        const char* wsrc = (const char*)wfrag + (size_t)h * 32768;
        #pragma unroll
        for (int i = 0; i < 8; ++i) {
            const int off = (wave * 8 + i) * 1024;
            GLOAD_LDS16(wsrc + off + lane * 16, smem + off);
        }
    }

    __syncthreads();

    f32x4 acc[4];
    #pragma unroll
    for (int n = 0; n < 4; ++n) {
        f32x4 z = {0.f, 0.f, 0.f, 0.f};
        acc[n] = z;
    }

    #pragma unroll
    for (int ks = 0; ks < 4; ++ks) {
        half8 ah, al;
        split8(g[ks][0], g[ks][1], ah, al);
        #pragma unroll
        for (int n = 0; n < 4; ++n) {
            const int fo = (ks * 4 + n) * 2048 + lane * 16;
            half8 bh = *reinterpret_cast<const half8*>(smem + fo);
            half8 bl = *reinterpret_cast<const half8*>(smem + fo + 1024);
            acc[n] = __builtin_amdgcn_mfma_f32_16x16x32_f16(ah, bh, acc[n], 0, 0, 0);
            acc[n] = __builtin_amdgcn_mfma_f32_16x16x32_f16(ah, bl, acc[n], 0, 0, 0);
            acc[n] = __builtin_amdgcn_mfma_f32_16x16x32_f16(al, bh, acc[n], 0, 0, 0);
        }
    }

    const float b0 = bias[h * NSTATE +  0 + col];
    const float b1 = bias[h * NSTATE + 16 + col];
    const float b2 = bias[h * NSTATE + 32 + col];
    const float b3 = bias[h * NSTATE + 48 + col];

    float sc[4] = {0.f, 0.f, 0.f, 0.f};
    int   cn[4] = {0, 0, 0, 0};

    #pragma unroll
    for (int rg = 0; rg < 4; ++rg) {
        float L0 = acc[0][rg] + b0;
        float L1 = acc[1][rg] + b1;
        float L2 = acc[2][rg] + b2;
        float L3 = acc[3][rg] + b3;

        unsigned long long k0 = ((unsigned long long)ordf(L0) << 6) | (unsigned)(63 - ( 0 + col));
        unsigned long long k1 = ((unsigned long long)ordf(L1) << 6) | (unsigned)(63 - (16 + col));
        unsigned long long k2 = ((unsigned long long)ordf(L2) << 6) | (unsigned)(63 - (32 + col));
        unsigned long long k3 = ((unsigned long long)ordf(L3) << 6) | (unsigned)(63 - (48 + col));
        unsigned long long ka = k0 > k1 ? k0 : k1;
        unsigned long long kb = k2 > k3 ? k2 : k3;
        unsigned long long kk = ka > kb ? ka : kb;
        #pragma unroll
        for (int d = 1; d <= 8; d <<= 1) {
            unsigned long long o = __shfl_xor(kk, d);
            kk = kk > o ? kk : o;
        }
        const int idx = 63 - (int)(kk & 63ull);

        float e0 = __expf(L0), e1 = __expf(L1), e2 = __expf(L2), e3 = __expf(L3);
        float sm = (e0 + e1) + (e2 + e3);
        #pragma unroll
        for (int d = 1; d <= 8; d <<= 1) sm += __shfl_xor(sm, d);
        const float rinv = __builtin_amdgcn_rcpf(sm);
        sc[0] += e0 * rinv; sc[1] += e1 * rinv;
        sc[2] += e2 * rinv; sc[3] += e3 * rinv;

        cn[0] += (idx ==  0 + col);
        cn[1] += (idx == 16 + col);
        cn[2] += (idx == 32 + col);
        cn[3] += (idx == 48 + col);

        if (col == 0) {
            const int t = tokb + (kg << 2) + rg;
            out[(size_t)t * NHEAD + h] = 1.0f;
            out[(size_t)TH + (size_t)t * NHEAD + h] = (float)idx;
        }
    }

    #pragma unroll
    for (int n = 0; n < 4; ++n) {
        sc[n] += __shfl_xor(sc[n], 16);
        sc[n] += __shfl_xor(sc[n], 32);
        cn[n] += __shfl_xor(cn[n], 16);
        cn[n] += __shfl_xor(cn[n], 32);
    }

    __syncthreads();
    float* redf = (float*)smem;
    int*   redi = (int*)(smem + 1024);
    if (kg == 0) {
        #pragma unroll
        for (int n = 0; n < 4; ++n) {
            redf[wave * 64 + n * 16 + col] = sc[n];
            redi[wave * 64 + n * 16 + col] = cn[n];
        }
    }
    __syncthreads();
    if (wave == 0) {
        const float s = redf[lane] + redf[64 + lane] + redf[128 + lane] + redf[192 + lane];
        const int   c = redi[lane] + redi[64 + lane] + redi[128 + lane] + redi[192 + lane];
        atomicAdd(ws_sums + h * NSTATE + lane, s);
        atomicAdd(ws_cnts + h * NSTATE + lane, c);
    }
}

__global__ void router_loss(const float* __restrict__ ws_sums,
                            const int*   __restrict__ ws_cnts,
                            float* __restrict__ out)
{
    const int tid = threadIdx.x;
    float part = 0.0f;
    for (int j = tid; j < NHEAD * NSTATE; j += 256)
        part += (float)ws_cnts[j] * ws_sums[j];
    #pragma unroll
    for (int k = 32; k >= 1; k >>= 1)
        part += __shfl_xor(part, k);
    __shared__ float red[4];
    const int wv = tid >> 6, lane = tid & 63;
    if (lane == 0) red[wv] = part;
    __syncthreads();
    if (tid == 0) {
        const float tot = red[0] + red[1] + red[2] + red[3];
        const float T = (float)TOKENS;
        out[2 * (size_t)TH] = tot * ((float)NSTATE / (T * T));
    }
}

// ---------------- probes (diagnostic only; write to scratch) ----------------

// P1: A-path only. Per iter = exactly one R10 A-tile read per wave, rotating
// 64-token windows. dur/16 ~= A-share of the router.
__global__ __launch_bounds__(256)
void probe_aload(const float* __restrict__ x, float* __restrict__ scr)
{
    __shared__ float dummy[8192];                 // 32 KB occupancy mirror
    const int blk = blockIdx.x, h = blk & 15, bi = blk >> 4;
    const int tid = threadIdx.x;
    const int wave = __builtin_amdgcn_readfirstlane(tid >> 6);
    const int lane = tid & 63, col = lane & 15, kg = lane >> 4;
    const size_t srow = (size_t)(NHEAD * DDIM);

    for (int it = 0; it < 16; ++it) {
        const int base = ((bi + it * 17) & 127) * 64 + wave * 16;
        const float* arow = x + (size_t)(base + col) * srow + h * DDIM + kg * 8;
        float s = 0.f;
        #pragma unroll
        for (int ks = 0; ks < 4; ++ks) {
            f32x4 a0 = *reinterpret_cast<const f32x4*>(arow + ks * 32);
            f32x4 a1 = *reinterpret_cast<const f32x4*>(arow + ks * 32 + 4);
            s += (a0[0] + a0[1] + a0[2] + a0[3]) + (a1[0] + a1[1] + a1[2] + a1[3]);
        }
        KEEP(s);
        if (it == 0) dummy[tid] = s;              // keep LDS allocated
    }
    __syncthreads();
    scr[(size_t)blk * 256 + tid] = dummy[tid ^ 1];
}

// P2: A + split + 48 MFMA (B from LDS). (P2 - P1*12/16)/12 ~= MFMA+split share.
__global__ __launch_bounds__(256)
void probe_mfma(const float* __restrict__ x, const half8* __restrict__ wfrag,
                float* __restrict__ scr)
{
    __shared__ __align__(16) unsigned char smem[32768];
    const int blk = blockIdx.x, h = blk & 15, bi = blk >> 4;
    const int tid = threadIdx.x;
    const int wave = __builtin_amdgcn_readfirstlane(tid >> 6);
    const int lane = tid & 63, col = lane & 15, kg = lane >> 4;
    const size_t srow = (size_t)(NHEAD * DDIM);

    {
        const char* wsrc = (const char*)wfrag + (size_t)h * 32768;
        #pragma unroll
        for (int i = 0; i < 8; ++i) {
            const int off = (wave * 8 + i) * 1024;
            GLOAD_LDS16(wsrc + off + lane * 16, smem + off);
        }
    }
    __syncthreads();

    f32x4 acc[4];
    #pragma unroll
    for (int n = 0; n < 4; ++n) { f32x4 z = {0.f,0.f,0.f,0.f}; acc[n] = z; }

    for (int it = 0; it < 12; ++it) {
        const int base = ((bi + it * 17) & 127) * 64 + wave * 16;
        const float* arow = x + (size_t)(base + col) * srow + h * DDIM + kg * 8;
        #pragma unroll
        for (int ks = 0; ks < 4; ++ks) {
            f32x4 a0 = *reinterpret_cast<const f32x4*>(arow + ks * 32);
            f32x4 a1 = *reinterpret_cast<const f32x4*>(arow + ks * 32 + 4);
            half8 ah, al;
            split8(a0, a1, ah, al);
            #pragma unroll
            for (int n = 0; n < 4; ++n) {
                const int fo = (ks * 4 + n) * 2048 + lane * 16;
                half8 bh = *reinterpret_cast<const half8*>(smem + fo);
                half8 bl = *reinterpret_cast<const half8*>(smem + fo + 1024);
                acc[n] = __builtin_amdgcn_mfma_f32_16x16x32_f16(ah, bh, acc[n], 0, 0, 0);
                acc[n] = __builtin_amdgcn_mfma_f32_16x16x32_f16(ah, bl, acc[n], 0, 0, 0);
                acc[n] = __builtin_amdgcn_mfma_f32_16x16x32_f16(al, bh, acc[n], 0, 0, 0);
            }
        }
    }
    float s = 0.f;
    #pragma unroll
    for (int n = 0; n < 4; ++n)
        s += acc[n][0] + acc[n][1] + acc[n][2] + acc[n][3];
    scr[(size_t)blk * 256 + tid] = s;
}

// P3: epilogue only (opaque inputs, exact chain). dur/12 ~= epilogue share.
__global__ __launch_bounds__(256)
void probe_epi(float* __restrict__ scr)
{
    __shared__ float dummy[8192];                 // 32 KB occupancy mirror
    const int blk = blockIdx.x;
    const int tid = threadIdx.x;
    const int lane = tid & 63, col = lane & 15;

    float sc[4] = {0.f,0.f,0.f,0.f};
    int   cn[4] = {0,0,0,0};

    for (int it = 0; it < 12; ++it) {
        #pragma unroll
        for (int rg = 0; rg < 4; ++rg) {
            float L0 = (float)((lane + rg * 17 + it * 29) & 63) * 0.13f - 2.f;
            float L1 = (float)((lane * 3 + rg * 5 + it * 7) & 63) * 0.11f - 1.f;
            float L2 = (float)((lane * 5 + rg * 3 + it * 11) & 63) * 0.09f;
            float L3 = (float)((lane * 7 + rg + it * 13) & 63) * 0.07f - 3.f;
            OPAQ(L0); OPAQ(L1); OPAQ(L2); OPAQ(L3);

            unsigned long long k0 = ((unsigned long long)ordf(L0) << 6) | (unsigned)(63 - ( 0 + col));
            unsigned long long k1 = ((unsigned long long)ordf(L1) << 6) | (unsigned)(63 - (16 + col));
            unsigned long long k2 = ((unsigned long long)ordf(L2) << 6) | (unsigned)(63 - (32 + col));
            unsigned long long k3 = ((unsigned long long)ordf(L3) << 6) | (unsigned)(63 - (48 + col));
            unsigned long long ka = k0 > k1 ? k0 : k1;
            unsigned long long kb = k2 > k3 ? k2 : k3;
            unsigned long long kk = ka > kb ? ka : kb;
            #pragma unroll
            for (int d = 1; d <= 8; d <<= 1) {
                unsigned long long o = __shfl_xor(kk, d);
                kk = kk > o ? kk : o;
            }
            const int idx = 63 - (int)(kk & 63ull);

            float e0 = __expf(L0), e1 = __expf(L1), e2 = __expf(L2), e3 = __expf(L3);
            float sm = (e0 + e1) + (e2 + e3);
            #pragma unroll
            for (int d = 1; d <= 8; d <<= 1) sm += __shfl_xor(sm, d);
            const float rinv = __builtin_amdgcn_rcpf(sm);
            sc[0] += e0 * rinv; sc[1] += e1 * rinv;
            sc[2] += e2 * rinv; sc[3] += e3 * rinv;
            cn[0] += (idx ==  0 + col);
            cn[1] += (idx == 16 + col);
            cn[2] += (idx == 32 + col);
            cn[3] += (idx == 48 + col);
        }
        if (it == 0) dummy[tid] = sc[0];
    }
    __syncthreads();
    scr[(size_t)blk * 256 + tid] = sc[0] + sc[1] + sc[2] + sc[3]
                                 + (float)(cn[0] + cn[1] + cn[2] + cn[3])
                                 + dummy[tid ^ 1];
}

// P4: out-stores + wave/block reduce + barriers + atomics. dur/64 ~= out share.
__global__ __launch_bounds__(256)
void probe_outred(float* __restrict__ scrout, float* __restrict__ scratomf,
                  int* __restrict__ scratomi, float* __restrict__ scr)
{
    __shared__ __align__(16) unsigned char smem[32768];
    const int blk = blockIdx.x, h = blk & 15, bi = blk >> 4;
    const int tid = threadIdx.x;
    const int wave = __builtin_amdgcn_readfirstlane(tid >> 6);
    const int lane = tid & 63, col = lane & 15, kg = lane >> 4;

    float* redf = (float*)smem;
    int*   redi = (int*)(smem + 1024);

    float acc = 0.f;
    for (int it = 0; it < 64; ++it) {
        const int tokb = ((bi + it * 17) & 127) * 64 + wave * 16;
        float sc[4]; int cn[4];
        #pragma unroll
        for (int n = 0; n < 4; ++n) { sc[n] = (float)(it + n); cn[n] = it + n; }

        if (col == 0) {
            #pragma unroll
            for (int rg = 0; rg < 4; ++rg) {
                const int t = tokb + (kg << 2) + rg;
                scrout[(size_t)t * NHEAD + h] = 1.0f;
                scrout[(size_t)TH + (size_t)t * NHEAD + h] = (float)it;
            }
        }
        #pragma unroll
        for (int n = 0; n < 4; ++n) {
            sc[n] += __shfl_xor(sc[n], 16);
            sc[n] += __shfl_xor(sc[n], 32);
            cn[n] += __shfl_xor(cn[n], 16);
            cn[n] += __shfl_xor(cn[n], 32);
        }
        __syncthreads();
        if (kg == 0) {
            #pragma unroll
            for (int n = 0; n < 4; ++n) {
                redf[wave * 64 + n * 16 + col] = sc[n];
                redi[wave * 64 + n * 16 + col] = cn[n];
            }
        }
        __syncthreads();
        if (wave == 0) {
            const float s = redf[lane] + redf[64 + lane] + redf[128 + lane] + redf[192 + lane];
            const int   c = redi[lane] + redi[64 + lane] + redi[128 + lane] + redi[192 + lane];
            atomicAdd(scratomf + h * NSTATE + lane, s);
            atomicAdd(scratomi + h * NSTATE + lane, c);
            acc += s;
        }
    }
    scr[(size_t)blk * 256 + tid] = acc;
}

extern "C" void kernel_launch(void* const* d_in, const int* in_sizes, int n_in,
                              void* d_out, int out_size, void* d_ws, size_t ws_size,
                              hipStream_t stream)
{
    const float* x    = (const float*)d_in[0];
    const float* w    = (const float*)d_in[1];
    const float* bias = (const float*)d_in[2];
    float* out = (float*)d_out;

    half8* wfrag   = (half8*)d_ws;
    float* ws_sums = (float*)((char*)d_ws + WFRAG_BYTES);
    int*   ws_cnts = (int*)((char*)d_ws + WFRAG_BYTES + 4096);

    char* scrbase  = (char*)d_ws + WFRAG_BYTES + 65536;
    float* scr      = (float*)scrbase;               // 2 MB probe dump
    float* scrout   = (float*)(scrbase + (4u << 20)); // 1 MB out mirror
    float* scratomf = (float*)(scrbase + (8u << 20));
    int*   scratomi = (int*)(scrbase + (8u << 20) + 4096);

    hipMemsetAsync((char*)d_ws + WFRAG_BYTES, 0, 8192, stream);

    // real pipeline (validated)
    prep_w<<<dim3(64), dim3(256), 0, stream>>>(w, wfrag);
    router_mfma<<<dim3(NBLK), dim3(256), 0, stream>>>(x, wfrag, bias, out,
                                                      ws_sums, ws_cnts);
    router_loss<<<dim3(1), dim3(256), 0, stream>>>(ws_sums, ws_cnts, out);

    // diagnostic probes (scratch only)
    probe_aload <<<dim3(NBLK), dim3(256), 0, stream>>>(x, scr);
    probe_mfma  <<<dim3(NBLK), dim3(256), 0, stream>>>(x, wfrag, scr);
    probe_epi   <<<dim3(NBLK), dim3(256), 0, stream>>>(scr);
    probe_outred<<<dim3(NBLK), dim3(256), 0, stream>>>(scrout, scratomf,
                                                       scratomi, scr);
}

// Round 13
// 36.848 us; speedup vs baseline: 13.9340x; 13.9340x over previous
//
#include <hip/hip_runtime.h>

// MultiHeadRouter: B=2, L=4096, H=16, S=64, D=128
// out (float32): [T*H ones][T*H argmax-as-float][1 loss], T = 8192
//
// R13: zero-barrier persistent router.
// - grid 512 = exactly 2 blocks/CU (64 KB LDS cap) -> all blocks co-resident.
// - B (W fragment planes) in 128 VGPRs, loaded once per wave.
// - A staged global->LDS (per-wave private dbuf, VGPR-free) with counted
//   vmcnt waits; NO __syncthreads in the whole main loop.
// - idx -> h-major scratch (coalesced); ones/transpose/loss in finale kernel
//   (P4 measured the scattered-store+atomic phase at 3.2us -> restructured).
// - atomics: 8-replica slots (16-way contention), zeroed by prep_w (no memset).
// f16 2-split MFMA chain + key-argmax epilogue bit-identical to R4-R12
// (absmax 0 x9).

#define TOKENS  8192
#define NHEAD   16
#define NSTATE  64
#define DDIM    128
#define TH      (TOKENS * NHEAD)

// d_ws layout
#define WFRAG_BYTES (1u << 19)                 // 512 KB fragment planes
#define REP_OFF     WFRAG_BYTES                // 64 KB: repf[8][1024], repc[8][1024]
#define REP_BYTES   65536
#define IDX_OFF     (WFRAG_BYTES + REP_BYTES)  // 512 KB idx_scr[16][8192]

typedef _Float16 half8 __attribute__((ext_vector_type(8)));
typedef float    f32x4 __attribute__((ext_vector_type(4)));

#define GLOAD_LDS16(gsrc, ldst)                                           \
    __builtin_amdgcn_global_load_lds(                                     \
        (const __attribute__((address_space(1))) void*)(gsrc),            \
        (__attribute__((address_space(3))) void*)(ldst), 16, 0, 0)

__device__ __forceinline__ unsigned int ordf(float f) {
    unsigned int u = __float_as_uint(f);
    return (u & 0x80000000u) ? ~u : (u | 0x80000000u);   // order-preserving
}

__device__ __forceinline__ void split8(const f32x4 v0, const f32x4 v1,
                                       half8& hh, half8& ll) {
    #pragma unroll
    for (int j = 0; j < 4; ++j) {
        _Float16 h0 = (_Float16)v0[j];
        hh[j]     = h0;  ll[j]     = (_Float16)(v0[j] - (float)h0);
        _Float16 h1 = (_Float16)v1[j];
        hh[4 + j] = h1;  ll[4 + j] = (_Float16)(v1[j] - (float)h1);
    }
}

// One-shot: W fp32 -> fragment-ordered f16 hi/lo planes (R7-verified layout)
// + zero the 64 KB atomic-replica region (replaces the memset dispatch).
__global__ __launch_bounds__(256)
void prep_w(const float* __restrict__ w, half8* __restrict__ wfrag,
            float* __restrict__ rep /* 16384 floats */)
{
    const int t    = blockIdx.x * 256 + threadIdx.x;   // 16384 threads
    rep[t] = 0.0f;
    const int lane = t & 63;
    const int n    = (t >> 6) & 3;
    const int ks   = (t >> 8) & 3;
    const int h    = t >> 10;
    const int s    = n * 16 + (lane & 15);
    const int k0   = ks * 32 + (lane >> 4) * 8;
    const float* src = w + (size_t)(h * NSTATE + s) * DDIM + k0;
    f32x4 v0 = *reinterpret_cast<const f32x4*>(src);
    f32x4 v1 = *reinterpret_cast<const f32x4*>(src + 4);
    half8 hv, lv;
    split8(v0, v1, hv, lv);
    const size_t hb = (size_t)h * 2048;
    const int fb = (ks * 4 + n) * 2;
    wfrag[hb + (size_t)fb * 64 + lane]       = hv;
    wfrag[hb + (size_t)(fb + 1) * 64 + lane] = lv;
}

__global__ __launch_bounds__(256, 2)   // min 2 waves/EU -> 256-VGPR cap
void router_mfma(const float* __restrict__ x,      // [T,H,D]
                 const half8* __restrict__ wfrag,  // fragment planes
                 const float* __restrict__ bias,   // [H,S]
                 float* __restrict__ idx_scr,      // [H][T] h-major idx
                 float* __restrict__ repf,         // [8][1024]
                 float* __restrict__ repc)         // [8][1024]
{
    // 64 KB: per-wave private A double-buffer [wave][buf][16 rows x 512 B],
    // source-XOR-swizzled (R9-verified pair). No other LDS use, no barriers.
    __shared__ __align__(16) unsigned char smem[65536];

    const int blk  = blockIdx.x;        // 512: bi-major (h = low bits)
    const int h    = blk & 15;
    const int win  = blk >> 4;          // 32 windows x 256 tokens
    const int tid  = threadIdx.x;
    const int wave = __builtin_amdgcn_readfirstlane(tid >> 6);
    const int lane = tid & 63;
    const int col  = lane & 15;         // A-row (token low) == B-state low bits
    const int kg   = lane >> 4;
    const int base = win * 256 + wave * 64;   // this wave's 64 tokens

    unsigned char* const Aw = smem + wave * 16384;
    const size_t srow = (size_t)(NHEAD * DDIM);

    // stage A tile `it` into buf: 8 x global_load_lds_dwordx4, VGPR-free.
    // LDS row r slot s holds source slot s^(r&7) (read side XORs the same).
    auto stageA = [&](int it, int buf) {
        const int tokb = base + it * 16;
        unsigned char* dst = Aw + buf * 8192;
        #pragma unroll
        for (int i = 0; i < 8; ++i) {
            const int r = i * 2 + (lane >> 5);
            const float* src = x + (size_t)(tokb + r) * srow + h * DDIM
                             + 4 * ((lane & 31) ^ (r & 7));
            GLOAD_LDS16(src, dst + i * 1024);
        }
    };

    stageA(0, 0);                       // x HBM reads first (longest latency)

    // B resident in 128 VGPRs: 32 fragments (hi/lo per ks,n), static indexing.
    half8 breg[32];
    #pragma unroll
    for (int f = 0; f < 32; ++f)
        breg[f] = wfrag[(size_t)h * 2048 + (size_t)f * 64 + lane];

    const float b0 = bias[h * NSTATE +  0 + col];
    const float b1 = bias[h * NSTATE + 16 + col];
    const float b2 = bias[h * NSTATE + 32 + col];
    const float b3 = bias[h * NSTATE + 48 + col];

    float sc[4] = {0.f, 0.f, 0.f, 0.f};
    int   cn[4] = {0, 0, 0, 0};

    #pragma unroll
    for (int it = 0; it < 4; ++it) {
        const int buf = it & 1;
        if (it < 3) stageA(it + 1, buf ^ 1);
        // vmcnt retires in issue order, so waiting until <=N outstanding
        // guarantees everything older than the newest N is done.
        // it=0: newest 8 = stage(1)      -> vmcnt(8) drains B-regs + stage(0)
        // it=1,2: newest 9 = store(it-1)+stage(it+1) -> vmcnt(9) drains stage(it)
        // it=3: newest 1 = store(2)      -> vmcnt(1) drains stage(3)
        if (it == 0)      asm volatile("s_waitcnt vmcnt(8)" ::: "memory");
        else if (it < 3)  asm volatile("s_waitcnt vmcnt(9)" ::: "memory");
        else              asm volatile("s_waitcnt vmcnt(1)" ::: "memory");

        f32x4 acc[4];
        #pragma unroll
        for (int n = 0; n < 4; ++n) {
            f32x4 z = {0.f, 0.f, 0.f, 0.f};
            acc[n] = z;
        }

        #pragma unroll
        for (int ks = 0; ks < 4; ++ks) {
            const int s0 = ks * 8 + kg * 2;
            const unsigned char* ab = Aw + buf * 8192 + col * 512;
            f32x4 a0 = *reinterpret_cast<const f32x4*>(ab + 16 * ( s0      ^ (col & 7)));
            f32x4 a1 = *reinterpret_cast<const f32x4*>(ab + 16 * ((s0 + 1) ^ (col & 7)));
            half8 ah, al;
            split8(a0, a1, ah, al);
            #pragma unroll
            for (int n = 0; n < 4; ++n) {   // chain order bit-identical R4-R12
                acc[n] = __builtin_amdgcn_mfma_f32_16x16x32_f16(ah, breg[(ks*4+n)*2],     acc[n], 0, 0, 0);
                acc[n] = __builtin_amdgcn_mfma_f32_16x16x32_f16(ah, breg[(ks*4+n)*2 + 1], acc[n], 0, 0, 0);
                acc[n] = __builtin_amdgcn_mfma_f32_16x16x32_f16(al, breg[(ks*4+n)*2],     acc[n], 0, 0, 0);
            }
        }

        // ---- epilogue (proven structure); idx -> coalesced h-major scratch ----
        const int tokb = base + it * 16;
        int my_idx = 0;
        #pragma unroll
        for (int rg = 0; rg < 4; ++rg) {
            float L0 = acc[0][rg] + b0;
            float L1 = acc[1][rg] + b1;
            float L2 = acc[2][rg] + b2;
            float L3 = acc[3][rg] + b3;

            unsigned long long k0 = ((unsigned long long)ordf(L0) << 6) | (unsigned)(63 - ( 0 + col));
            unsigned long long k1 = ((unsigned long long)ordf(L1) << 6) | (unsigned)(63 - (16 + col));
            unsigned long long k2 = ((unsigned long long)ordf(L2) << 6) | (unsigned)(63 - (32 + col));
            unsigned long long k3 = ((unsigned long long)ordf(L3) << 6) | (unsigned)(63 - (48 + col));
            unsigned long long ka = k0 > k1 ? k0 : k1;
            unsigned long long kb = k2 > k3 ? k2 : k3;
            unsigned long long kk = ka > kb ? ka : kb;
            #pragma unroll
            for (int d = 1; d <= 8; d <<= 1) {
                unsigned long long o = __shfl_xor(kk, d);
                kk = kk > o ? kk : o;
            }
            const int idx = 63 - (int)(kk & 63ull);

            float e0 = __expf(L0), e1 = __expf(L1), e2 = __expf(L2), e3 = __expf(L3);
            float sm = (e0 + e1) + (e2 + e3);
            #pragma unroll
            for (int d = 1; d <= 8; d <<= 1) sm += __shfl_xor(sm, d);
            const float rinv = __builtin_amdgcn_rcpf(sm);
            sc[0] += e0 * rinv; sc[1] += e1 * rinv;
            sc[2] += e2 * rinv; sc[3] += e3 * rinv;

            cn[0] += (idx ==  0 + col);
            cn[1] += (idx == 16 + col);
            cn[2] += (idx == 32 + col);
            cn[3] += (idx == 48 + col);

            if (col == rg) my_idx = idx;    // owner lane captures its token
        }
        // 16 owner lanes (kg*4+col, col<4) -> 64 contiguous bytes
        if (col < 4)
            idx_scr[(size_t)h * TOKENS + tokb + (kg << 2) + col] = (float)my_idx;
    }

    // wave reduce over kg groups, then 8 atomics to a contention-diluted replica
    #pragma unroll
    for (int n = 0; n < 4; ++n) {
        sc[n] += __shfl_xor(sc[n], 16);
        sc[n] += __shfl_xor(sc[n], 32);
        cn[n] += __shfl_xor(cn[n], 16);
        cn[n] += __shfl_xor(cn[n], 32);
    }
    if (kg == 0) {
        const int rep = ((blk << 2) | wave) & 7;
        #pragma unroll
        for (int n = 0; n < 4; ++n) {
            atomicAdd(repf + rep * 1024 + h * 64 + n * 16 + col, sc[n]);
            atomicAdd(repc + rep * 1024 + h * 64 + n * 16 + col, (float)cn[n]);
        }
    }
}

// finale: blocks 0-31 transpose idx_scr->out + fill ones plane (full-line
// writes); block 32 reduces the 8 replicas into the loss scalar.
__global__ __launch_bounds__(256)
void finale(const float* __restrict__ idx_scr,
            const float* __restrict__ repf,
            const float* __restrict__ repc,
            float* __restrict__ out)
{
    const int b   = blockIdx.x;
    const int tid = threadIdx.x;

    if (b < 32) {
        __shared__ float tl[256 * 17];      // padded: conflict-free transpose
        #pragma unroll
        for (int hh = 0; hh < 16; ++hh)
            tl[tid * 17 + hh] = idx_scr[(size_t)hh * TOKENS + b * 256 + tid];
        __syncthreads();
        #pragma unroll
        for (int k = 0; k < 16; ++k) {
            const int i = k * 256 + tid;    // 4096 outputs per block
            out[(size_t)TH + (size_t)b * 4096 + i] = tl[(i >> 4) * 17 + (i & 15)];
            out[(size_t)b * 4096 + i] = 1.0f;
        }
    } else {
        float part = 0.0f;
        for (int j = tid; j < NHEAD * NSTATE; j += 256) {
            float cf = 0.f, cc = 0.f;
            #pragma unroll
            for (int r = 0; r < 8; ++r) {
                cf += repf[r * 1024 + j];
                cc += repc[r * 1024 + j];
            }
            part += cf * cc;
        }
        #pragma unroll
        for (int d = 1; d <= 32; d <<= 1)
            part += __shfl_xor(part, d);
        __shared__ float red[4];
        const int wv = tid >> 6, lane = tid & 63;
        if (lane == 0) red[wv] = part;
        __syncthreads();
        if (tid == 0) {
            const float tot = red[0] + red[1] + red[2] + red[3];
            const float T = (float)TOKENS;
            out[2 * (size_t)TH] = tot * ((float)NSTATE / (T * T));
        }
    }
}

extern "C" void kernel_launch(void* const* d_in, const int* in_sizes, int n_in,
                              void* d_out, int out_size, void* d_ws, size_t ws_size,
                              hipStream_t stream)
{
    const float* x    = (const float*)d_in[0];
    const float* w    = (const float*)d_in[1];
    const float* bias = (const float*)d_in[2];
    float* out = (float*)d_out;

    half8* wfrag   = (half8*)d_ws;
    float* rep     = (float*)((char*)d_ws + REP_OFF);       // repf(32K)+repc(32K)
    float* repf    = rep;
    float* repc    = rep + 8192;
    float* idx_scr = (float*)((char*)d_ws + IDX_OFF);

    prep_w<<<dim3(64), dim3(256), 0, stream>>>(w, wfrag, rep);
    router_mfma<<<dim3(512), dim3(256), 0, stream>>>(x, wfrag, bias,
                                                     idx_scr, repf, repc);
    finale<<<dim3(33), dim3(256), 0, stream>>>(idx_scr, repf, repc, out);
}

// Round 14
// 30.426 us; speedup vs baseline: 16.8747x; 1.2110x over previous
//
#include <hip/hip_runtime.h>

// MultiHeadRouter: B=2, L=4096, H=16, S=64, D=128
// out (float32): [T*H ones][T*H argmax-as-float][1 loss], T = 8192
//
// R14: persistent AND deep. Session diagnosis: every prior round ran at
// 1.3-2.5 waves/SIMD (launch-ramp-limited short blocks, or 2-block/CU LDS
// caps) -> all latencies exposed. This round: 1024 uniform blocks (4/CU
// co-resident), LDS = 32 KB B-planes only (5-block/CU cap -> allocator
// VGPR budget ~102 >= demand ~81), wave = 2 sequential 16-token tiles,
// A direct-to-VGPR (no prefetch; TLP at 4 waves/SIMD hides the stall).
// No inline asm. One barrier. R13's coalesced idx scratch + replica
// atomics + finale kept (P4-measured). f16 2-split MFMA chain + key-argmax
// epilogue bit-identical to R4-R13 (absmax 0 x10).

#define TOKENS  8192
#define NHEAD   16
#define NSTATE  64
#define DDIM    128
#define TH      (TOKENS * NHEAD)

// d_ws layout
#define WFRAG_BYTES (1u << 19)                 // 512 KB fragment planes
#define REP_OFF     WFRAG_BYTES                // 64 KB: repf[8][1024], repc[8][1024]
#define REP_BYTES   65536
#define IDX_OFF     (WFRAG_BYTES + REP_BYTES)  // 512 KB idx_scr[16][8192]

typedef _Float16 half8 __attribute__((ext_vector_type(8)));
typedef float    f32x4 __attribute__((ext_vector_type(4)));

#define GLOAD_LDS16(gsrc, ldst)                                           \
    __builtin_amdgcn_global_load_lds(                                     \
        (const __attribute__((address_space(1))) void*)(gsrc),            \
        (__attribute__((address_space(3))) void*)(ldst), 16, 0, 0)

__device__ __forceinline__ unsigned int ordf(float f) {
    unsigned int u = __float_as_uint(f);
    return (u & 0x80000000u) ? ~u : (u | 0x80000000u);   // order-preserving
}

__device__ __forceinline__ void split8(const f32x4 v0, const f32x4 v1,
                                       half8& hh, half8& ll) {
    #pragma unroll
    for (int j = 0; j < 4; ++j) {
        _Float16 h0 = (_Float16)v0[j];
        hh[j]     = h0;  ll[j]     = (_Float16)(v0[j] - (float)h0);
        _Float16 h1 = (_Float16)v1[j];
        hh[4 + j] = h1;  ll[4 + j] = (_Float16)(v1[j] - (float)h1);
    }
}

// One-shot: W fp32 -> fragment-ordered f16 hi/lo planes (R7-verified layout)
// + zero the atomic-replica region (replaces a memset dispatch).
__global__ __launch_bounds__(256)
void prep_w(const float* __restrict__ w, half8* __restrict__ wfrag,
            float* __restrict__ rep /* 16384 floats */)
{
    const int t    = blockIdx.x * 256 + threadIdx.x;   // 16384 threads
    rep[t] = 0.0f;
    const int lane = t & 63;
    const int n    = (t >> 6) & 3;
    const int ks   = (t >> 8) & 3;
    const int h    = t >> 10;
    const int s    = n * 16 + (lane & 15);
    const int k0   = ks * 32 + (lane >> 4) * 8;
    const float* src = w + (size_t)(h * NSTATE + s) * DDIM + k0;
    f32x4 v0 = *reinterpret_cast<const f32x4*>(src);
    f32x4 v1 = *reinterpret_cast<const f32x4*>(src + 4);
    half8 hv, lv;
    split8(v0, v1, hv, lv);
    const size_t hb = (size_t)h * 2048;
    const int fb = (ks * 4 + n) * 2;
    wfrag[hb + (size_t)fb * 64 + lane]       = hv;
    wfrag[hb + (size_t)(fb + 1) * 64 + lane] = lv;
}

__global__ __launch_bounds__(256)
void router_mfma(const float* __restrict__ x,      // [T,H,D]
                 const half8* __restrict__ wfrag,  // fragment planes
                 const float* __restrict__ bias,   // [H,S]
                 float* __restrict__ idx_scr,      // [H][T] h-major idx
                 float* __restrict__ repf,         // [8][1024]
                 float* __restrict__ repc)         // [8][1024]
{
    // 32 KB: B fragment planes only. 5-block/CU LDS cap -> allocator VGPR
    // budget ~102; demand ~81 -> no spill. We launch 4/CU (uniform blocks).
    __shared__ __align__(16) unsigned char smem[32768];

    const int blk  = blockIdx.x;        // 1024: h = low 4 bits (bi-major)
    const int h    = blk & 15;
    const int grp  = blk >> 4;          // 64 groups x 128 tokens
    const int tid  = threadIdx.x;
    const int wave = __builtin_amdgcn_readfirstlane(tid >> 6);
    const int lane = tid & 63;
    const int col  = lane & 15;         // A-row (token low) == B-state low bits
    const int kg   = lane >> 4;
    const int base = grp * 128;

    // ---- stage B once per block: 32 KB linear copy (L2-hot), VGPR-free ----
    {
        const char* wsrc = (const char*)wfrag + (size_t)h * 32768;
        #pragma unroll
        for (int i = 0; i < 8; ++i) {
            const int off = (wave * 8 + i) * 1024;
            GLOAD_LDS16(wsrc + off + lane * 16, smem + off);
        }
    }

    const float b0 = bias[h * NSTATE +  0 + col];
    const float b1 = bias[h * NSTATE + 16 + col];
    const float b2 = bias[h * NSTATE + 32 + col];
    const float b3 = bias[h * NSTATE + 48 + col];

    __syncthreads();   // the only barrier: B planes ready

    const size_t srow = (size_t)(NHEAD * DDIM);
    float sc[4] = {0.f, 0.f, 0.f, 0.f};
    int   cn[4] = {0, 0, 0, 0};

    #pragma unroll
    for (int tt = 0; tt < 2; ++tt) {    // 2 sequential tiles per wave
        const int tokb = base + (wave + 4 * tt) * 16;

        // A: 8 x dwordx4 global->VGPR (all in flight; TLP hides the wait)
        const float* arow = x + (size_t)(tokb + col) * srow + h * DDIM + kg * 8;
        f32x4 g[4][2];
        #pragma unroll
        for (int ks = 0; ks < 4; ++ks) {
            g[ks][0] = *reinterpret_cast<const f32x4*>(arow + ks * 32);
            g[ks][1] = *reinterpret_cast<const f32x4*>(arow + ks * 32 + 4);
        }

        f32x4 acc[4];
        #pragma unroll
        for (int n = 0; n < 4; ++n) {
            f32x4 z = {0.f, 0.f, 0.f, 0.f};
            acc[n] = z;
        }

        #pragma unroll
        for (int ks = 0; ks < 4; ++ks) {
            half8 ah, al;
            split8(g[ks][0], g[ks][1], ah, al);
            #pragma unroll
            for (int n = 0; n < 4; ++n) {   // chain order bit-identical R4-R13
                const int fo = (ks * 4 + n) * 2048 + lane * 16;
                half8 bh = *reinterpret_cast<const half8*>(smem + fo);
                half8 bl = *reinterpret_cast<const half8*>(smem + fo + 1024);
                acc[n] = __builtin_amdgcn_mfma_f32_16x16x32_f16(ah, bh, acc[n], 0, 0, 0);
                acc[n] = __builtin_amdgcn_mfma_f32_16x16x32_f16(ah, bl, acc[n], 0, 0, 0);
                acc[n] = __builtin_amdgcn_mfma_f32_16x16x32_f16(al, bh, acc[n], 0, 0, 0);
            }
        }

        // ---- epilogue (absmax-0-verified structure) ----
        int my_idx = 0;
        #pragma unroll
        for (int rg = 0; rg < 4; ++rg) {
            float L0 = acc[0][rg] + b0;
            float L1 = acc[1][rg] + b1;
            float L2 = acc[2][rg] + b2;
            float L3 = acc[3][rg] + b3;

            unsigned long long k0 = ((unsigned long long)ordf(L0) << 6) | (unsigned)(63 - ( 0 + col));
            unsigned long long k1 = ((unsigned long long)ordf(L1) << 6) | (unsigned)(63 - (16 + col));
            unsigned long long k2 = ((unsigned long long)ordf(L2) << 6) | (unsigned)(63 - (32 + col));
            unsigned long long k3 = ((unsigned long long)ordf(L3) << 6) | (unsigned)(63 - (48 + col));
            unsigned long long ka = k0 > k1 ? k0 : k1;
            unsigned long long kb = k2 > k3 ? k2 : k3;
            unsigned long long kk = ka > kb ? ka : kb;
            #pragma unroll
            for (int d = 1; d <= 8; d <<= 1) {
                unsigned long long o = __shfl_xor(kk, d);
                kk = kk > o ? kk : o;
            }
            const int idx = 63 - (int)(kk & 63ull);

            float e0 = __expf(L0), e1 = __expf(L1), e2 = __expf(L2), e3 = __expf(L3);
            float sm = (e0 + e1) + (e2 + e3);
            #pragma unroll
            for (int d = 1; d <= 8; d <<= 1) sm += __shfl_xor(sm, d);
            const float rinv = __builtin_amdgcn_rcpf(sm);
            sc[0] += e0 * rinv; sc[1] += e1 * rinv;
            sc[2] += e2 * rinv; sc[3] += e3 * rinv;

            cn[0] += (idx ==  0 + col);
            cn[1] += (idx == 16 + col);
            cn[2] += (idx == 32 + col);
            cn[3] += (idx == 48 + col);

            if (col == rg) my_idx = idx;    // owner lane captures its token
        }
        // 16 owner lanes (col<4) -> 64 contiguous bytes per tile
        if (col < 4)
            idx_scr[(size_t)h * TOKENS + tokb + (kg << 2) + col] = (float)my_idx;
    }

    // wave reduce over kg groups -> replica atomics (contention-diluted)
    #pragma unroll
    for (int n = 0; n < 4; ++n) {
        sc[n] += __shfl_xor(sc[n], 16);
        sc[n] += __shfl_xor(sc[n], 32);
        cn[n] += __shfl_xor(cn[n], 16);
        cn[n] += __shfl_xor(cn[n], 32);
    }
    if (kg == 0) {
        const int rep = ((blk << 2) | wave) & 7;
        #pragma unroll
        for (int n = 0; n < 4; ++n) {
            atomicAdd(repf + rep * 1024 + h * 64 + n * 16 + col, sc[n]);
            atomicAdd(repc + rep * 1024 + h * 64 + n * 16 + col, (float)cn[n]);
        }
    }
}

// finale: blocks 0-31 transpose idx_scr->out + fill ones plane (full-line
// writes); block 32 reduces the 8 replicas into the loss scalar.
__global__ __launch_bounds__(256)
void finale(const float* __restrict__ idx_scr,
            const float* __restrict__ repf,
            const float* __restrict__ repc,
            float* __restrict__ out)
{
    const int b   = blockIdx.x;
    const int tid = threadIdx.x;

    if (b < 32) {
        __shared__ float tl[256 * 17];      // padded: conflict-free transpose
        #pragma unroll
        for (int hh = 0; hh < 16; ++hh)
            tl[tid * 17 + hh] = idx_scr[(size_t)hh * TOKENS + b * 256 + tid];
        __syncthreads();
        #pragma unroll
        for (int k = 0; k < 16; ++k) {
            const int i = k * 256 + tid;    // 4096 outputs per block
            out[(size_t)TH + (size_t)b * 4096 + i] = tl[(i >> 4) * 17 + (i & 15)];
            out[(size_t)b * 4096 + i] = 1.0f;
        }
    } else {
        float part = 0.0f;
        for (int j = tid; j < NHEAD * NSTATE; j += 256) {
            float cf = 0.f, cc = 0.f;
            #pragma unroll
            for (int r = 0; r < 8; ++r) {
                cf += repf[r * 1024 + j];
                cc += repc[r * 1024 + j];
            }
            part += cf * cc;
        }
        #pragma unroll
        for (int d = 1; d <= 32; d <<= 1)
            part += __shfl_xor(part, d);
        __shared__ float red[4];
        const int wv = tid >> 6, lane = tid & 63;
        if (lane == 0) red[wv] = part;
        __syncthreads();
        if (tid == 0) {
            const float tot = red[0] + red[1] + red[2] + red[3];
            const float T = (float)TOKENS;
            out[2 * (size_t)TH] = tot * ((float)NSTATE / (T * T));
        }
    }
}

extern "C" void kernel_launch(void* const* d_in, const int* in_sizes, int n_in,
                              void* d_out, int out_size, void* d_ws, size_t ws_size,
                              hipStream_t stream)
{
    const float* x    = (const float*)d_in[0];
    const float* w    = (const float*)d_in[1];
    const float* bias = (const float*)d_in[2];
    float* out = (float*)d_out;

    half8* wfrag   = (half8*)d_ws;
    float* rep     = (float*)((char*)d_ws + REP_OFF);
    float* repf    = rep;
    float* repc    = rep + 8192;
    float* idx_scr = (float*)((char*)d_ws + IDX_OFF);

    prep_w<<<dim3(64), dim3(256), 0, stream>>>(w, wfrag, rep);
    router_mfma<<<dim3(1024), dim3(256), 0, stream>>>(x, wfrag, bias,
                                                      idx_scr, repf, repc);
    finale<<<dim3(33), dim3(256), 0, stream>>>(idx_scr, repf, repc, out);
}

// Round 15
// 28.971 us; speedup vs baseline: 17.7226x; 1.0502x over previous
//
#include <hip/hip_runtime.h>

// MultiHeadRouter: B=2, L=4096, H=16, S=64, D=128
// out (float32): [T*H ones][T*H argmax-as-float][1 loss], T = 8192
//
// R15 = R14 pushed to the hardware occupancy cap.
// 512-thread blocks (8 waves), grid 1024 -> 4 blocks/CU = 2048 threads/CU
// (thread cap) = 32 waves/CU = 8 waves/SIMD. LDS 32 KB B-planes x4 = 128 KB
// <= 160. One 16-token tile per wave (8192 tiles, one uniform pass).
// A streamed 2 x f32x4 per ks -> register demand ~65; the allocator's
// max-occupancy squeeze (R2/R6/R8 ledger) lands at ~64 VGPR = 8 waves/SIMD,
// and 8-way TLP covers the per-wave serialization (mechanism validated R14).
// f16 2-split MFMA chain + key-argmax epilogue bit-identical R4-R14
// (absmax 0 x11).

#define TOKENS  8192
#define NHEAD   16
#define NSTATE  64
#define DDIM    128
#define TH      (TOKENS * NHEAD)

// d_ws layout
#define WFRAG_BYTES (1u << 19)                 // 512 KB fragment planes
#define REP_OFF     WFRAG_BYTES                // 64 KB: repf[8][1024], repc[8][1024]
#define REP_BYTES   65536
#define IDX_OFF     (WFRAG_BYTES + REP_BYTES)  // 512 KB idx_scr[16][8192]

typedef _Float16 half8 __attribute__((ext_vector_type(8)));
typedef float    f32x4 __attribute__((ext_vector_type(4)));

#define GLOAD_LDS16(gsrc, ldst)                                           \
    __builtin_amdgcn_global_load_lds(                                     \
        (const __attribute__((address_space(1))) void*)(gsrc),            \
        (__attribute__((address_space(3))) void*)(ldst), 16, 0, 0)

__device__ __forceinline__ unsigned int ordf(float f) {
    unsigned int u = __float_as_uint(f);
    return (u & 0x80000000u) ? ~u : (u | 0x80000000u);   // order-preserving
}

__device__ __forceinline__ void split8(const f32x4 v0, const f32x4 v1,
                                       half8& hh, half8& ll) {
    #pragma unroll
    for (int j = 0; j < 4; ++j) {
        _Float16 h0 = (_Float16)v0[j];
        hh[j]     = h0;  ll[j]     = (_Float16)(v0[j] - (float)h0);
        _Float16 h1 = (_Float16)v1[j];
        hh[4 + j] = h1;  ll[4 + j] = (_Float16)(v1[j] - (float)h1);
    }
}

// One-shot: W fp32 -> fragment-ordered f16 hi/lo planes (R7-verified layout)
// + zero the atomic-replica region (replaces a memset dispatch).
__global__ __launch_bounds__(256)
void prep_w(const float* __restrict__ w, half8* __restrict__ wfrag,
            float* __restrict__ rep /* 16384 floats */)
{
    const int t    = blockIdx.x * 256 + threadIdx.x;   // 16384 threads
    rep[t] = 0.0f;
    const int lane = t & 63;
    const int n    = (t >> 6) & 3;
    const int ks   = (t >> 8) & 3;
    const int h    = t >> 10;
    const int s    = n * 16 + (lane & 15);
    const int k0   = ks * 32 + (lane >> 4) * 8;
    const float* src = w + (size_t)(h * NSTATE + s) * DDIM + k0;
    f32x4 v0 = *reinterpret_cast<const f32x4*>(src);
    f32x4 v1 = *reinterpret_cast<const f32x4*>(src + 4);
    half8 hv, lv;
    split8(v0, v1, hv, lv);
    const size_t hb = (size_t)h * 2048;
    const int fb = (ks * 4 + n) * 2;
    wfrag[hb + (size_t)fb * 64 + lane]       = hv;
    wfrag[hb + (size_t)(fb + 1) * 64 + lane] = lv;
}

__global__ __launch_bounds__(512)
void router_mfma(const float* __restrict__ x,      // [T,H,D]
                 const half8* __restrict__ wfrag,  // fragment planes
                 const float* __restrict__ bias,   // [H,S]
                 float* __restrict__ idx_scr,      // [H][T] h-major idx
                 float* __restrict__ repf,         // [8][1024]
                 float* __restrict__ repc)         // [8][1024]
{
    // 32 KB: B fragment planes, shared by 8 waves.
    __shared__ __align__(16) unsigned char smem[32768];

    const int blk  = blockIdx.x;        // 1024: h = low 4 bits (bi-major)
    const int h    = blk & 15;
    const int grp  = blk >> 4;          // 64 groups x 128 tokens per head
    const int tid  = threadIdx.x;
    const int wave = __builtin_amdgcn_readfirstlane(tid >> 6);   // 0..7
    const int lane = tid & 63;
    const int col  = lane & 15;         // A-row (token low) == B-state low bits
    const int kg   = lane >> 4;
    const int tokb = grp * 128 + wave * 16;   // this wave's single tile

    // ---- stage B once per block: 32 KB linear copy, 512 threads x 4 x 16B ----
    {
        const char* wsrc = (const char*)wfrag + (size_t)h * 32768;
        #pragma unroll
        for (int i = 0; i < 4; ++i) {
            const int off = (i * 512 + tid) * 16;
            GLOAD_LDS16(wsrc + off, smem + off);
        }
    }

    const float b0 = bias[h * NSTATE +  0 + col];
    const float b1 = bias[h * NSTATE + 16 + col];
    const float b2 = bias[h * NSTATE + 32 + col];
    const float b3 = bias[h * NSTATE + 48 + col];

    __syncthreads();   // the only barrier: B planes ready

    const size_t srow = (size_t)(NHEAD * DDIM);
    const float* arow = x + (size_t)(tokb + col) * srow + h * DDIM + kg * 8;

    f32x4 acc[4];
    #pragma unroll
    for (int n = 0; n < 4; ++n) {
        f32x4 z = {0.f, 0.f, 0.f, 0.f};
        acc[n] = z;
    }

    // streamed A: 2 x f32x4 per ks (low reg demand; 8-way TLP hides latency)
    #pragma unroll
    for (int ks = 0; ks < 4; ++ks) {
        f32x4 g0 = *reinterpret_cast<const f32x4*>(arow + ks * 32);
        f32x4 g1 = *reinterpret_cast<const f32x4*>(arow + ks * 32 + 4);
        half8 ah, al;
        split8(g0, g1, ah, al);
        #pragma unroll
        for (int n = 0; n < 4; ++n) {   // chain order bit-identical R4-R14
            const int fo = (ks * 4 + n) * 2048 + lane * 16;
            half8 bh = *reinterpret_cast<const half8*>(smem + fo);
            half8 bl = *reinterpret_cast<const half8*>(smem + fo + 1024);
            acc[n] = __builtin_amdgcn_mfma_f32_16x16x32_f16(ah, bh, acc[n], 0, 0, 0);
            acc[n] = __builtin_amdgcn_mfma_f32_16x16x32_f16(ah, bl, acc[n], 0, 0, 0);
            acc[n] = __builtin_amdgcn_mfma_f32_16x16x32_f16(al, bh, acc[n], 0, 0, 0);
        }
    }

    // ---- epilogue (absmax-0-verified structure) ----
    float sc[4] = {0.f, 0.f, 0.f, 0.f};
    int   cn[4] = {0, 0, 0, 0};
    int   my_idx = 0;

    #pragma unroll
    for (int rg = 0; rg < 4; ++rg) {
        float L0 = acc[0][rg] + b0;
        float L1 = acc[1][rg] + b1;
        float L2 = acc[2][rg] + b2;
        float L3 = acc[3][rg] + b3;

        unsigned long long k0 = ((unsigned long long)ordf(L0) << 6) | (unsigned)(63 - ( 0 + col));
        unsigned long long k1 = ((unsigned long long)ordf(L1) << 6) | (unsigned)(63 - (16 + col));
        unsigned long long k2 = ((unsigned long long)ordf(L2) << 6) | (unsigned)(63 - (32 + col));
        unsigned long long k3 = ((unsigned long long)ordf(L3) << 6) | (unsigned)(63 - (48 + col));
        unsigned long long ka = k0 > k1 ? k0 : k1;
        unsigned long long kb = k2 > k3 ? k2 : k3;
        unsigned long long kk = ka > kb ? ka : kb;
        #pragma unroll
        for (int d = 1; d <= 8; d <<= 1) {
            unsigned long long o = __shfl_xor(kk, d);
            kk = kk > o ? kk : o;
        }
        const int idx = 63 - (int)(kk & 63ull);

        float e0 = __expf(L0), e1 = __expf(L1), e2 = __expf(L2), e3 = __expf(L3);
        float sm = (e0 + e1) + (e2 + e3);
        #pragma unroll
        for (int d = 1; d <= 8; d <<= 1) sm += __shfl_xor(sm, d);
        const float rinv = __builtin_amdgcn_rcpf(sm);
        sc[0] += e0 * rinv; sc[1] += e1 * rinv;
        sc[2] += e2 * rinv; sc[3] += e3 * rinv;

        cn[0] += (idx ==  0 + col);
        cn[1] += (idx == 16 + col);
        cn[2] += (idx == 32 + col);
        cn[3] += (idx == 48 + col);

        if (col == rg) my_idx = idx;    // owner lane captures its token
    }
    // 16 owner lanes (col<4) -> 64 contiguous bytes
    if (col < 4)
        idx_scr[(size_t)h * TOKENS + tokb + (kg << 2) + col] = (float)my_idx;

    // wave reduce over kg groups -> replica atomics (contention-diluted)
    #pragma unroll
    for (int n = 0; n < 4; ++n) {
        sc[n] += __shfl_xor(sc[n], 16);
        sc[n] += __shfl_xor(sc[n], 32);
        cn[n] += __shfl_xor(cn[n], 16);
        cn[n] += __shfl_xor(cn[n], 32);
    }
    if (kg == 0) {
        const int rep = ((blk << 3) | wave) & 7;
        #pragma unroll
        for (int n = 0; n < 4; ++n) {
            atomicAdd(repf + rep * 1024 + h * 64 + n * 16 + col, sc[n]);
            atomicAdd(repc + rep * 1024 + h * 64 + n * 16 + col, (float)cn[n]);
        }
    }
}

// finale: blocks 0-31 transpose idx_scr->out + fill ones plane (full-line
// writes); block 32 reduces the 8 replicas into the loss scalar.
__global__ __launch_bounds__(256)
void finale(const float* __restrict__ idx_scr,
            const float* __restrict__ repf,
            const float* __restrict__ repc,
            float* __restrict__ out)
{
    const int b   = blockIdx.x;
    const int tid = threadIdx.x;

    if (b < 32) {
        __shared__ float tl[256 * 17];      // padded: conflict-free transpose
        #pragma unroll
        for (int hh = 0; hh < 16; ++hh)
            tl[tid * 17 + hh] = idx_scr[(size_t)hh * TOKENS + b * 256 + tid];
        __syncthreads();
        #pragma unroll
        for (int k = 0; k < 16; ++k) {
            const int i = k * 256 + tid;    // 4096 outputs per block
            out[(size_t)TH + (size_t)b * 4096 + i] = tl[(i >> 4) * 17 + (i & 15)];
            out[(size_t)b * 4096 + i] = 1.0f;
        }
    } else {
        float part = 0.0f;
        for (int j = tid; j < NHEAD * NSTATE; j += 256) {
            float cf = 0.f, cc = 0.f;
            #pragma unroll
            for (int r = 0; r < 8; ++r) {
                cf += repf[r * 1024 + j];
                cc += repc[r * 1024 + j];
            }
            part += cf * cc;
        }
        #pragma unroll
        for (int d = 1; d <= 32; d <<= 1)
            part += __shfl_xor(part, d);
        __shared__ float red[4];
        const int wv = tid >> 6, lane = tid & 63;
        if (lane == 0) red[wv] = part;
        __syncthreads();
        if (tid == 0) {
            const float tot = red[0] + red[1] + red[2] + red[3];
            const float T = (float)TOKENS;
            out[2 * (size_t)TH] = tot * ((float)NSTATE / (T * T));
        }
    }
}

extern "C" void kernel_launch(void* const* d_in, const int* in_sizes, int n_in,
                              void* d_out, int out_size, void* d_ws, size_t ws_size,
                              hipStream_t stream)
{
    const float* x    = (const float*)d_in[0];
    const float* w    = (const float*)d_in[1];
    const float* bias = (const float*)d_in[2];
    float* out = (float*)d_out;

    half8* wfrag   = (half8*)d_ws;
    float* rep     = (float*)((char*)d_ws + REP_OFF);
    float* repf    = rep;
    float* repc    = rep + 8192;
    float* idx_scr = (float*)((char*)d_ws + IDX_OFF);

    prep_w<<<dim3(64), dim3(256), 0, stream>>>(w, wfrag, rep);
    router_mfma<<<dim3(1024), dim3(512), 0, stream>>>(x, wfrag, bias,
                                                      idx_scr, repf, repc);
    finale<<<dim3(33), dim3(256), 0, stream>>>(idx_scr, repf, repc, out);
}